// Round 1
// 416.237 us; speedup vs baseline: 1.0300x; 1.0300x over previous
//
#include <hip/hip_runtime.h>
#include <cstddef>

#define SZ    8192
#define DELN  2048
#define SOFF  6144              // SZ - DELN
#define BASE2 12582912          // SOFF * DELN
#define TINV  0.1f
#define FEPS  1e-20f

// fused-grid role layout:
//   [0, NBR)            : BR tiles (few, latency-bound -> dispatch FIRST)
//   [NBR, NBR+4608)     : groups of 3 = {TR, TR, Z}  (interleave read-heavy with write-only)
#define NBR   528               // 32*33/2 upper-triangular 64x64 tiles of BR
#define NTR   3072              // 96 row-tiles x 32 col-tiles of TR
#define NZ    1536              // zero blocks: 4 rows x 6144 cols each (96 KB/block)
#define NGRID (NBR + NTR + NZ)  // 5136

__device__ __forceinline__ float gsig(float a0, float a1, float u0, float u1) {
    // gumbel-softmax component 0 of a 2-way softmax == sigmoid((x0-x1))
    float g0 = -__logf(-__logf(u0 + FEPS) + FEPS);
    float g1 = -__logf(-__logf(u1 + FEPS) + FEPS);
    float d  = (a0 + g0 - a1 - g1) * TINV;
    return __fdividef(1.0f, 1.0f + __expf(-d));
}

__device__ __forceinline__ long br_base(int ti) {
    // e(ti,tj) = br_base(ti) + tj ; valid for ti < tj
    return (long)BASE2 + (long)ti * (DELN - 1) - ((long)ti * (ti - 1)) / 2 - (long)ti - 1;
}

__global__ __launch_bounds__(256) void k_fused(const float* __restrict__ gen,
                                               const float* __restrict__ uu,
                                               float* __restrict__ out) {
    __shared__ float tile[64][65];
    const int bid = blockIdx.x;
    const int c4  = threadIdx.x & 15;
    const int r   = threadIdx.x >> 4;   // 0..15
    const int lc  = c4 * 4;

    if (bid >= NBR) {
        const int b2 = bid - NBR;       // 0..4607
        const int g  = b2 / 3;          // 0..1535 (magic-mul div)
        const int p  = b2 - g * 3;      // 0..2

        if (p == 2) {
            // ---------------- Z role: rows [g*4, g*4+4) x cols [0,6144) ----------------
            const int lane = threadIdx.x & 63;
            const int w    = threadIdx.x >> 6;   // wave id 0..3 -> one row each
            float4* rowp = (float4*)(out + (size_t)(g * 4 + w) * SZ);
            const float4 z4 = make_float4(0.f, 0.f, 0.f, 0.f);
            #pragma unroll
            for (int k = 0; k < 24; ++k)         // 24*64 = 1536 float4 = 6144 cols
                rowp[k * 64 + lane] = z4;        // 1 KB contiguous per wave-iteration
            return;
        }

        // ---------------- TR role (i<S, j>=S) + mirrored BL via LDS transpose ----------
        const int t  = g * 2 + p;       // 0..3071
        const int tJ = t & 31;          // col tile
        const int tI = t >> 5;          // row tile, 0..95
        const int i0 = tI * 64;
        const int jb = tJ * 64;

        #pragma unroll
        for (int it = 0; it < 4; ++it) {
            const int li = r + 16 * it;
            const int i  = i0 + li;
            const size_t e0 = (size_t)i * DELN + (size_t)(jb + lc);  // mult of 4 -> 16B aligned
            const float4* gp = (const float4*)(gen + 2 * e0);
            const float4* up = (const float4*)(uu  + 2 * e0);
            float4 ga = gp[0], gb = gp[1];
            float4 ua = up[0], ub = up[1];
            float v0 = gsig(ga.x, ga.y, ua.x, ua.y);
            float v1 = gsig(ga.z, ga.w, ua.z, ua.w);
            float v2 = gsig(gb.x, gb.y, ub.x, ub.y);
            float v3 = gsig(gb.z, gb.w, ub.z, ub.w);
            tile[li][lc] = v0; tile[li][lc+1] = v1; tile[li][lc+2] = v2; tile[li][lc+3] = v3;
            *(float4*)(out + (size_t)i * SZ + (size_t)(SOFF + jb + lc)) =
                make_float4(v0, v1, v2, v3);
        }
        __syncthreads();
        // mirror: rows SOFF+jb+lj, cols i0..i0+63
        #pragma unroll
        for (int it = 0; it < 4; ++it) {
            const int lj  = r + 16 * it;
            const int row = SOFF + jb + lj;
            float4 v = make_float4(tile[lc][lj], tile[lc+1][lj], tile[lc+2][lj], tile[lc+3][lj]);
            *(float4*)(out + (size_t)row * SZ + (size_t)(i0 + lc)) = v;
        }
        return;
    }

    // ---------------- BR role (both >= S): triu(k=1), symmetrized, zero diag ----------
    int rem = bid;
    int tI = 0;
    while (rem >= 32 - tI) { rem -= 32 - tI; ++tI; }
    const int tJ  = tI + rem;
    const int ti0 = tI * 64;
    const int tj0 = tJ * 64;
    const bool diag = (tI == tJ);

    #pragma unroll
    for (int it = 0; it < 4; ++it) {
        const int li = r + 16 * it;
        const int ti = ti0 + li;
        const long eb = br_base(ti) + (long)(tj0 + lc);
        float v[4];
        #pragma unroll
        for (int k = 0; k < 4; ++k) {
            const int tj = tj0 + lc + k;
            if (!diag || ti < tj) {
                const long e = eb + k;
                float2 g = *(const float2*)(gen + 2 * e);   // 8B aligned always
                float2 w = *(const float2*)(uu  + 2 * e);
                v[k] = gsig(g.x, g.y, w.x, w.y);
            } else {
                v[k] = 0.0f;                                 // diagonal / lower of diag tile
            }
        }
        tile[li][lc] = v[0]; tile[li][lc+1] = v[1]; tile[li][lc+2] = v[2]; tile[li][lc+3] = v[3];
        if (!diag) {
            *(float4*)(out + (size_t)(SOFF + ti) * SZ + (size_t)(SOFF + tj0 + lc)) =
                make_float4(v[0], v[1], v[2], v[3]);
        }
    }
    __syncthreads();
    if (diag) {
        // full tile: upper from compute, diag zero, lower mirrored within tile
        #pragma unroll
        for (int it = 0; it < 4; ++it) {
            const int li = r + 16 * it;
            float4 v;
            float* pv = &v.x;
            #pragma unroll
            for (int k = 0; k < 4; ++k) {
                const int ltj = lc + k;
                pv[k] = (li <= ltj) ? tile[li][ltj] : tile[ltj][li];
            }
            *(float4*)(out + (size_t)(SOFF + ti0 + li) * SZ + (size_t)(SOFF + tj0 + lc)) = v;
        }
    } else {
        // mirror tile: rows SOFF+tj0+lj, cols SOFF+ti0..+63
        #pragma unroll
        for (int it = 0; it < 4; ++it) {
            const int lj = r + 16 * it;
            float4 v = make_float4(tile[lc][lj], tile[lc+1][lj], tile[lc+2][lj], tile[lc+3][lj]);
            *(float4*)(out + (size_t)(SOFF + tj0 + lj) * SZ + (size_t)(SOFF + ti0 + lc)) = v;
        }
    }
}

extern "C" void kernel_launch(void* const* d_in, const int* in_sizes, int n_in,
                              void* d_out, int out_size, void* d_ws, size_t ws_size,
                              hipStream_t stream) {
    const float* gen = (const float*)d_in[0];   // (E,2) fp32
    const float* uu  = (const float*)d_in[1];   // (E,2) fp32
    float* out = (float*)d_out;                 // (8192,8192) fp32

    k_fused<<<dim3(NGRID), 256, 0, stream>>>(gen, uu, out);
}